// Round 1
// baseline (656.262 us; speedup 1.0000x reference)
//
#include <hip/hip_runtime.h>

// KPConv fused kernel, f32 (CDNA4 has no fp32 MFMA -> vector ALU).
// N=50000 queries, M=50000 supports, KNN=32, K=15 kernel pts, C_IN=64, C_OUT=128.
// Block = 256 threads (4 waves), QB=16 queries/block, grid = 3125 (exact).
// Phase 1: wave-per-query: h[k][e] -> LDS, neighbor count, kf[15] per lane in regs.
// Phase 2: 3 rounds of 5 kernel points: dump kf chunk to LDS, register-tiled GEMM
//          (4 outputs x 2 queries per thread) against L2-resident weights.

namespace {
constexpr int NQ   = 50000;
constexpr int MS   = 50000;
constexpr int KNN  = 32;
constexpr int KP   = 15;
constexpr int CIN  = 64;
constexpr int COUT = 128;
constexpr int QB   = 16;                 // queries per block
constexpr int CHUNK_E = 5;               // kernel points per phase-2 round
constexpr int CHUNK_I = CHUNK_E * CIN;   // 320 rows per round
constexpr int KF_PAD  = 18;              // q-column stride (even -> float2 reads)
constexpr float KP_EXT_INV = 1.0f / 1.2f;
}

__global__ __launch_bounds__(256, 3)
void kpconv_fused(const float* __restrict__ q_pts,
                  const float* __restrict__ s_pts,
                  const float* __restrict__ s_feats,
                  const int*   __restrict__ neigh,
                  const float* __restrict__ W,
                  const float* __restrict__ kpts,
                  float*       __restrict__ out)
{
    __shared__ __align__(16) float kf_c[CHUNK_I * KF_PAD];  // 23040 B
    __shared__ __align__(16) float h_lds[4][KNN][20];       // 10240 B (pad 20: 16B-aligned rows)
    __shared__ float dxyz[4][KNN][3];                       // 1536 B
    __shared__ int   idxl[4][KNN];                          // 512 B
    __shared__ float kp_s[48];                              // 192 B
    __shared__ float norm_s[QB];                            // 64 B

    const int tid  = threadIdx.x;
    const int lane = tid & 63;
    const int wv   = tid >> 6;
    const int blk  = blockIdx.x;
    const int k32  = lane & 31;
    const int half = lane >> 5;

    if (tid < KP * 3) kp_s[tid] = kpts[tid];
    __syncthreads();

    // kf accumulators for this wave's 4 queries, lane = input channel
    float kfv[4][KP];

    // ---------------- Phase 1 ----------------
    #pragma unroll
    for (int j = 0; j < 4; ++j) {
        const int q = wv * 4 + j;
        const int n = blk * QB + q;
        const float qx = q_pts[n * 3 + 0];
        const float qy = q_pts[n * 3 + 1];
        const float qz = q_pts[n * 3 + 2];

        // 1a: lanes 0..31 gather neighbor index + point delta (shadow -> 1e6)
        if (lane < KNN) {
            int idx = neigh[n * KNN + k32];
            idxl[wv][k32] = idx;
            int  ic    = idx < MS ? idx : MS - 1;
            bool valid = idx < MS;
            float px = s_pts[ic * 3 + 0];
            float py = s_pts[ic * 3 + 1];
            float pz = s_pts[ic * 3 + 2];
            dxyz[wv][k32][0] = valid ? px - qx : 1e6f;
            dxyz[wv][k32][1] = valid ? py - qy : 1e6f;
            dxyz[wv][k32][2] = valid ? pz - qz : 1e6f;
        }
        __builtin_amdgcn_wave_barrier();

        // 1b: h[k][e] = max(0, 1 - sqrt(d2+1e-8)/1.2), 480 pairs over 8 passes
        const float dx = dxyz[wv][k32][0];
        const float dy = dxyz[wv][k32][1];
        const float dz = dxyz[wv][k32][2];
        #pragma unroll
        for (int p = 0; p < 8; ++p) {
            const int e = (p << 1) + half;
            if (e < KP) {
                float ax = dx - kp_s[e * 3 + 0];
                float ay = dy - kp_s[e * 3 + 1];
                float az = dz - kp_s[e * 3 + 2];
                float d2 = ax * ax + ay * ay + az * az + 1e-8f;
                float hh = 1.0f - sqrtf(d2) * KP_EXT_INV;
                h_lds[wv][k32][e] = hh > 0.0f ? hh : 0.0f;
            }
        }
        __builtin_amdgcn_wave_barrier();

        // 1c: neighbor count: lane (k,half) sums 32 channels, combine halves
        {
            int  idx   = idxl[wv][k32];
            bool valid = idx < MS;
            int  ic    = valid ? idx : MS - 1;
            const float4* rp = (const float4*)(s_feats + (size_t)ic * CIN + half * 32);
            float4 s4 = rp[0];
            #pragma unroll
            for (int t = 1; t < 8; ++t) {
                float4 a = rp[t];
                s4.x += a.x; s4.y += a.y; s4.z += a.z; s4.w += a.w;
            }
            float s = (s4.x + s4.y) + (s4.z + s4.w);
            s += __shfl_xor(s, 32);
            bool flag = valid && (s > 0.0f);
            unsigned long long b = __ballot(flag);   // 64-bit on CDNA
            int cnt = (int)(__popcll(b) >> 1);       // halves duplicate each k
            if (lane == 0) norm_s[q] = 1.0f / (float)(cnt > 1 ? cnt : 1);
        }

        // 1d: kf[e] += h[k][e] * feat[k][lane]; rows are L1-hot from 1c
        #pragma unroll
        for (int e = 0; e < KP; ++e) kfv[j][e] = 0.0f;
        #pragma unroll 4
        for (int k = 0; k < KNN; ++k) {
            int idx = idxl[wv][k];
            int ic  = idx < MS ? idx : MS - 1;      // h==0 for shadow -> safe
            float nf = s_feats[(size_t)ic * CIN + lane];
            const float4* hr = (const float4*)(&h_lds[wv][k][0]);
            float4 h0 = hr[0], h1 = hr[1], h2 = hr[2], h3 = hr[3];
            kfv[j][0]  += h0.x * nf;  kfv[j][1]  += h0.y * nf;
            kfv[j][2]  += h0.z * nf;  kfv[j][3]  += h0.w * nf;
            kfv[j][4]  += h1.x * nf;  kfv[j][5]  += h1.y * nf;
            kfv[j][6]  += h1.z * nf;  kfv[j][7]  += h1.w * nf;
            kfv[j][8]  += h2.x * nf;  kfv[j][9]  += h2.y * nf;
            kfv[j][10] += h2.z * nf;  kfv[j][11] += h2.w * nf;
            kfv[j][12] += h3.x * nf;  kfv[j][13] += h3.y * nf;
            kfv[j][14] += h3.z * nf;
        }
    }

    // ---------------- Phase 2: out = kf · W in 3 e-chunk rounds ----------------
    const int o4 = tid & 31;        // 4 consecutive outputs at o = 4*o4
    const int qi = tid >> 5;        // queries 2*qi, 2*qi+1
    const int q0 = qi * 2, q1 = q0 + 1;

    float4 tot0 = make_float4(0.f, 0.f, 0.f, 0.f);
    float4 tot1 = make_float4(0.f, 0.f, 0.f, 0.f);

    #pragma unroll
    for (int r = 0; r < 3; ++r) {
        __syncthreads();            // prior round's reads complete before overwrite
        // dump this wave's kf chunk: rows i = e5*64 + lane, column q
        #pragma unroll
        for (int j = 0; j < 4; ++j) {
            const int q = wv * 4 + j;
            #pragma unroll
            for (int e5 = 0; e5 < CHUNK_E; ++e5) {
                kf_c[(e5 * CIN + lane) * KF_PAD + q] = kfv[j][r * CHUNK_E + e5];
            }
        }
        __syncthreads();

        const float* wb = W + (size_t)(r * CHUNK_I) * COUT + (o4 << 2);
        float4 a0 = make_float4(0.f, 0.f, 0.f, 0.f);
        float4 a1 = make_float4(0.f, 0.f, 0.f, 0.f);
        float4 b0 = make_float4(0.f, 0.f, 0.f, 0.f);
        float4 b1 = make_float4(0.f, 0.f, 0.f, 0.f);
        #pragma unroll 8
        for (int il = 0; il < CHUNK_I; il += 2) {
            float4 w4 = *(const float4*)(wb + il * COUT);
            float2 kA = *(const float2*)(kf_c + il * KF_PAD + q0);       // broadcast
            a0.x += w4.x * kA.x; a0.y += w4.y * kA.x;
            a0.z += w4.z * kA.x; a0.w += w4.w * kA.x;
            a1.x += w4.x * kA.y; a1.y += w4.y * kA.y;
            a1.z += w4.z * kA.y; a1.w += w4.w * kA.y;
            float4 v4 = *(const float4*)(wb + (il + 1) * COUT);
            float2 kB = *(const float2*)(kf_c + (il + 1) * KF_PAD + q0);
            b0.x += v4.x * kB.x; b0.y += v4.y * kB.x;
            b0.z += v4.z * kB.x; b0.w += v4.w * kB.x;
            b1.x += v4.x * kB.y; b1.y += v4.y * kB.y;
            b1.z += v4.z * kB.y; b1.w += v4.w * kB.y;
        }
        tot0.x += a0.x + b0.x; tot0.y += a0.y + b0.y;
        tot0.z += a0.z + b0.z; tot0.w += a0.w + b0.w;
        tot1.x += a1.x + b1.x; tot1.y += a1.y + b1.y;
        tot1.z += a1.z + b1.z; tot1.w += a1.w + b1.w;
    }

    // epilogue: normalize by valid-neighbor count, coalesced float4 stores
    const float nm0 = norm_s[q0];
    const float nm1 = norm_s[q1];
    const size_t base = (size_t)(blk * QB) * COUT + (o4 << 2);
    float4 r0 = make_float4(tot0.x * nm0, tot0.y * nm0, tot0.z * nm0, tot0.w * nm0);
    float4 r1 = make_float4(tot1.x * nm1, tot1.y * nm1, tot1.z * nm1, tot1.w * nm1);
    *(float4*)(out + base + (size_t)q0 * COUT) = r0;
    *(float4*)(out + base + (size_t)q1 * COUT) = r1;
}

extern "C" void kernel_launch(void* const* d_in, const int* in_sizes, int n_in,
                              void* d_out, int out_size, void* d_ws, size_t ws_size,
                              hipStream_t stream) {
    const float* q_pts   = (const float*)d_in[0];
    const float* s_pts   = (const float*)d_in[1];
    const float* s_feats = (const float*)d_in[2];
    const int*   neigh   = (const int*)d_in[3];
    const float* W       = (const float*)d_in[4];
    const float* kpts    = (const float*)d_in[5];
    float* outp = (float*)d_out;

    dim3 grid(NQ / QB);   // 3125, exact
    dim3 block(256);
    hipLaunchKernelGGL(kpconv_fused, grid, block, 0, stream,
                       q_pts, s_pts, s_feats, neigh, W, kpts, outp);
}

// Round 2
// 470.743 us; speedup vs baseline: 1.3941x; 1.3941x over previous
//
#include <hip/hip_runtime.h>

// KPConv fused, f32 (no fp32 MFMA on CDNA4 -> vector ALU).
// R2 changes vs R1:
//  - rowsum precompute kernel (d_ws) removes the duplicate s_feats gather for the count
//  - LDS union of phase-1 scratch and phase-2 kf buffer: 35.8KB -> ~20.5KB (7 blocks/CU LDS-limit)
//  - sparsity: skip neighbors whose h-row is all zero (~40% of (q,k) pairs) via ballot mask + ctz loop
//  - phase-2 kf stored pair-interleaved + XOR-swizzled: 1x ds_read_b128 per 2 rows x 2 queries

namespace {
constexpr int NQ   = 50000;
constexpr int MS   = 50000;
constexpr int KNN  = 32;
constexpr int KP   = 15;
constexpr int CIN  = 64;
constexpr int COUT = 128;
constexpr int QB   = 16;                  // queries per block
constexpr int CHUNK_E = 5;                // kernel points per phase-2 round
constexpr int CHUNK_I = CHUNK_E * CIN;    // 320 rows
constexpr int NPAIR   = CHUNK_I / 2;      // 160 row-pairs
constexpr float KP_EXT_INV = 1.0f / 1.2f;
}

__global__ __launch_bounds__(256)
void rowsum_kernel(const float* __restrict__ s_feats, float* __restrict__ rs)
{
    int t = blockIdx.x * 256 + threadIdx.x;
    int row = t >> 3;
    int l8  = t & 7;
    if (row >= MS) return;
    const float4* p = (const float4*)(s_feats + (size_t)row * CIN + l8 * 8);
    float4 a = p[0], b = p[1];
    float s = ((a.x + a.y) + (a.z + a.w)) + ((b.x + b.y) + (b.z + b.w));
    s += __shfl_xor(s, 1);
    s += __shfl_xor(s, 2);
    s += __shfl_xor(s, 4);
    if (l8 == 0) rs[row] = s;
}

template<bool USE_RS>
__global__ __launch_bounds__(256, 6)
void kpconv_fused(const float* __restrict__ q_pts,
                  const float* __restrict__ s_pts,
                  const float* __restrict__ s_feats,
                  const int*   __restrict__ neigh,
                  const float* __restrict__ W,
                  const float* __restrict__ kpts,
                  const float* __restrict__ rowsum,
                  float*       __restrict__ out)
{
    // ---- LDS union: phase-1 scratch and phase-2 kf chunk share smem ----
    __shared__ __align__(16) float smem[NPAIR * 32];   // 20480 B
    __shared__ float norm_s[QB];                       // persists to epilogue

    float (*h_lds)[KNN][20]  = (float (*)[KNN][20])smem;            // [4][32][20] = 2560 f
    float (*dxyz)[KNN][3]    = (float (*)[KNN][3])(smem + 2560);    // 384 f
    int*   idxl              = (int*)(smem + 2944);                 // 128
    float* kp_s              = smem + 3072;                         // 45

    const int tid  = threadIdx.x;
    const int lane = tid & 63;
    const int wv   = tid >> 6;
    const int blk  = blockIdx.x;
    const int k32  = lane & 31;
    const int half = lane >> 5;

    if (tid < KP * 3) kp_s[tid] = kpts[tid];
    __syncthreads();

    float kfv[4][KP];   // lane = input channel

    // ---------------- Phase 1: wave-per-query ----------------
    #pragma unroll
    for (int j = 0; j < 4; ++j) {
        const int q = wv * 4 + j;
        const int n = blk * QB + q;
        const float qx = q_pts[n * 3 + 0];
        const float qy = q_pts[n * 3 + 1];
        const float qz = q_pts[n * 3 + 2];

        // 1a: lanes 0..31 gather index, point delta, and (USE_RS) count flag
        bool flag = false;
        if (lane < KNN) {
            int idx = neigh[n * KNN + k32];
            idxl[wv * KNN + k32] = idx;
            bool valid = idx < MS;
            int  ic    = valid ? idx : MS - 1;
            float px = s_pts[ic * 3 + 0];
            float py = s_pts[ic * 3 + 1];
            float pz = s_pts[ic * 3 + 2];
            dxyz[wv][k32][0] = valid ? px - qx : 1e6f;
            dxyz[wv][k32][1] = valid ? py - qy : 1e6f;
            dxyz[wv][k32][2] = valid ? pz - qz : 1e6f;
            if (USE_RS) flag = valid && (rowsum[ic] > 0.0f);
        }
        if (USE_RS) {
            unsigned long long b = __ballot(flag);
            int cnt = (int)__popcll(b);
            if (lane == 0) norm_s[q] = 1.0f / (float)(cnt > 1 ? cnt : 1);
        }
        __builtin_amdgcn_wave_barrier();

        // 1b: h[k][e] = max(0, 1 - sqrt(d2+1e-8)/1.2); also per-k any(h>0) mask
        const float dx = dxyz[wv][k32][0];
        const float dy = dxyz[wv][k32][1];
        const float dz = dxyz[wv][k32][2];
        float om = 0.0f;
        #pragma unroll
        for (int p = 0; p < 8; ++p) {
            const int e = (p << 1) + half;
            if (e < KP) {
                float ax = dx - kp_s[e * 3 + 0];
                float ay = dy - kp_s[e * 3 + 1];
                float az = dz - kp_s[e * 3 + 2];
                float d2 = ax * ax + ay * ay + az * az + 1e-8f;
                float hh = 1.0f - sqrtf(d2) * KP_EXT_INV;
                hh = hh > 0.0f ? hh : 0.0f;
                h_lds[wv][k32][e] = hh;
                om = fmaxf(om, hh);
            }
        }
        om = fmaxf(om, __shfl_xor(om, 32));
        unsigned long long bh = __ballot(om > 0.0f);
        unsigned int kmask = (unsigned int)bh;   // low 32 bits == per-k flags
        __builtin_amdgcn_wave_barrier();

        // 1c fallback (no workspace): full-row sums for the count
        if (!USE_RS) {
            int  idx   = idxl[wv * KNN + k32];
            bool valid = idx < MS;
            int  ic    = valid ? idx : MS - 1;
            const float4* rp = (const float4*)(s_feats + (size_t)ic * CIN + half * 32);
            float4 s4 = rp[0];
            #pragma unroll
            for (int t = 1; t < 8; ++t) {
                float4 a = rp[t];
                s4.x += a.x; s4.y += a.y; s4.z += a.z; s4.w += a.w;
            }
            float s = (s4.x + s4.y) + (s4.z + s4.w);
            s += __shfl_xor(s, 32);
            bool f2 = valid && (s > 0.0f);
            unsigned long long b = __ballot(f2);
            int cnt = (int)(__popcll(b) >> 1);
            if (lane == 0) norm_s[q] = 1.0f / (float)(cnt > 1 ? cnt : 1);
        }

        // 1d: kf[e] += h[k][e] * feat[k][lane], only over k with any h>0
        #pragma unroll
        for (int e = 0; e < KP; ++e) kfv[j][e] = 0.0f;
        unsigned int mk = kmask;
        while (mk) {
            int k = __builtin_ctz(mk);
            mk &= mk - 1;
            int idx2 = idxl[wv * KNN + k];
            int ic2  = idx2 < MS ? idx2 : MS - 1;   // h row nonzero => valid anyway
            float nf = s_feats[(size_t)ic2 * CIN + lane];
            const float4* hr = (const float4*)(&h_lds[wv][k][0]);
            float4 h0 = hr[0], h1 = hr[1], h2 = hr[2], h3 = hr[3];
            kfv[j][0]  += h0.x * nf;  kfv[j][1]  += h0.y * nf;
            kfv[j][2]  += h0.z * nf;  kfv[j][3]  += h0.w * nf;
            kfv[j][4]  += h1.x * nf;  kfv[j][5]  += h1.y * nf;
            kfv[j][6]  += h1.z * nf;  kfv[j][7]  += h1.w * nf;
            kfv[j][8]  += h2.x * nf;  kfv[j][9]  += h2.y * nf;
            kfv[j][10] += h2.z * nf;  kfv[j][11] += h2.w * nf;
            kfv[j][12] += h3.x * nf;  kfv[j][13] += h3.y * nf;
            kfv[j][14] += h3.z * nf;
        }
    }

    // ---------------- Phase 2: out = kf · W, 3 rounds of 5 kernel points ----------------
    // kf layout: pair p = i>>1 of rows (i, i+1); slot qs = q ^ (p & 14), element (i&1).
    // float4 read at [p*32 + (q0^m)*2] = (kf[2p][q0], kf[2p+1][q0], kf[2p][q1], kf[2p+1][q1]).
    const int o4 = tid & 31;          // output quad: o = 4*o4
    const int qi = tid >> 5;          // query pair
    const int q0 = qi * 2, q1 = q0 + 1;

    float4 tot0 = make_float4(0.f, 0.f, 0.f, 0.f);
    float4 tot1 = make_float4(0.f, 0.f, 0.f, 0.f);

    #pragma unroll
    for (int r = 0; r < 3; ++r) {
        __syncthreads();              // phase-1 data / prior round reads complete
        #pragma unroll
        for (int j = 0; j < 4; ++j) {
            const int q = wv * 4 + j;
            #pragma unroll
            for (int e5 = 0; e5 < CHUNK_E; ++e5) {
                int i  = e5 * CIN + lane;
                int pr = i >> 1;
                int m  = pr & 14;
                smem[pr * 32 + ((q ^ m) << 1) + (i & 1)] = kfv[j][r * CHUNK_E + e5];
            }
        }
        __syncthreads();

        const float* wb = W + (size_t)(r * CHUNK_I) * COUT + (o4 << 2);
        float4 acc0 = make_float4(0.f, 0.f, 0.f, 0.f);
        float4 acc1 = make_float4(0.f, 0.f, 0.f, 0.f);
        #pragma unroll 4
        for (int p = 0; p < NPAIR; ++p) {
            float4 kk = *(const float4*)(smem + p * 32 + ((q0 ^ (p & 14)) << 1));
            float4 w0 = *(const float4*)(wb + (size_t)(2 * p) * COUT);
            float4 w1 = *(const float4*)(wb + (size_t)(2 * p + 1) * COUT);
            acc0.x += w0.x * kk.x; acc0.y += w0.y * kk.x;
            acc0.z += w0.z * kk.x; acc0.w += w0.w * kk.x;
            acc1.x += w0.x * kk.z; acc1.y += w0.y * kk.z;
            acc1.z += w0.z * kk.z; acc1.w += w0.w * kk.z;
            acc0.x += w1.x * kk.y; acc0.y += w1.y * kk.y;
            acc0.z += w1.z * kk.y; acc0.w += w1.w * kk.y;
            acc1.x += w1.x * kk.w; acc1.y += w1.y * kk.w;
            acc1.z += w1.z * kk.w; acc1.w += w1.w * kk.w;
        }
        tot0.x += acc0.x; tot0.y += acc0.y; tot0.z += acc0.z; tot0.w += acc0.w;
        tot1.x += acc1.x; tot1.y += acc1.y; tot1.z += acc1.z; tot1.w += acc1.w;
    }

    // epilogue: normalize, coalesced float4 stores
    const float nm0 = norm_s[q0];
    const float nm1 = norm_s[q1];
    const size_t base = (size_t)(blk * QB) * COUT + (o4 << 2);
    float4 r0 = make_float4(tot0.x * nm0, tot0.y * nm0, tot0.z * nm0, tot0.w * nm0);
    float4 r1 = make_float4(tot1.x * nm1, tot1.y * nm1, tot1.z * nm1, tot1.w * nm1);
    *(float4*)(out + base + (size_t)q0 * COUT) = r0;
    *(float4*)(out + base + (size_t)q1 * COUT) = r1;
}

extern "C" void kernel_launch(void* const* d_in, const int* in_sizes, int n_in,
                              void* d_out, int out_size, void* d_ws, size_t ws_size,
                              hipStream_t stream) {
    const float* q_pts   = (const float*)d_in[0];
    const float* s_pts   = (const float*)d_in[1];
    const float* s_feats = (const float*)d_in[2];
    const int*   neigh   = (const int*)d_in[3];
    const float* W       = (const float*)d_in[4];
    const float* kpts    = (const float*)d_in[5];
    float* outp = (float*)d_out;

    dim3 grid(NQ / QB);   // 3125, exact
    dim3 block(256);

    if (ws_size >= MS * sizeof(float)) {
        float* rs = (float*)d_ws;
        int rs_blocks = (MS * 8 + 255) / 256;
        hipLaunchKernelGGL(rowsum_kernel, dim3(rs_blocks), dim3(256), 0, stream,
                           s_feats, rs);
        hipLaunchKernelGGL(kpconv_fused<true>, grid, block, 0, stream,
                           q_pts, s_pts, s_feats, neigh, W, kpts, rs, outp);
    } else {
        hipLaunchKernelGGL(kpconv_fused<false>, grid, block, 0, stream,
                           q_pts, s_pts, s_feats, neigh, W, kpts, (const float*)nullptr, outp);
    }
}

// Round 3
// 173.054 us; speedup vs baseline: 3.7922x; 2.7202x over previous
//
#include <hip/hip_runtime.h>

// KPConv fused, R3: stage-B GEMM moved to split-bf16 MFMA (hi/lo decomposition,
// 3 mfma_f32_16x16x32_bf16 passes, f32 accumulate). W pre-split into B-fragment
// layout in d_ws by a helper kernel; kf staged per-round in LDS in A-fragment order.
// Phase 1 (aggregation + neighbor count via rowsum) unchanged from R2.

namespace {
constexpr int NQ   = 50000;
constexpr int MS   = 50000;
constexpr int KNN  = 32;
constexpr int KP   = 15;
constexpr int CIN  = 64;
constexpr int COUT = 128;
constexpr int QB   = 16;                 // queries per block (one MFMA m-tile)
constexpr int ROWS = KP * CIN;           // 960 contraction rows
constexpr int RND  = 3;                  // phase-2 rounds
constexpr int RE   = 5;                  // kernel points per round
constexpr int RROWS = RE * CIN;          // 320 rows per round
constexpr int KBR  = RROWS / 32;         // 10 k-blocks per round
constexpr int KBT  = ROWS / 32;          // 30 k-blocks total
constexpr int NT   = COUT / 16;          // 8 n-tiles
constexpr int ASTR = RROWS + 4;          // 324: LDS kf row stride (16B-aligned, bank-skewed)
constexpr float KP_EXT_INV = 1.0f / 1.2f;
constexpr size_t WS_HI  = 200704;                    // after 50000*4 rowsum, 16B aligned
constexpr size_t WS_LO  = WS_HI + (size_t)ROWS * COUT * 2;   // +245760
constexpr size_t WS_NEED = WS_LO + (size_t)ROWS * COUT * 2;  // 692224 B
}

typedef __attribute__((ext_vector_type(8))) short short8;
typedef __attribute__((ext_vector_type(4))) float f32x4;

__device__ __forceinline__ short f32_bf16(float x) {
    unsigned u = __builtin_bit_cast(unsigned, x);
    u = u + 0x7fffu + ((u >> 16) & 1u);          // round-to-nearest-even
    return (short)(u >> 16);
}
__device__ __forceinline__ float bf16_f32(short h) {
    unsigned u = ((unsigned)(unsigned short)h) << 16;
    return __builtin_bit_cast(float, u);
}

// ---- helper 1: per-row feature sums (for neighbor_num) ----
__global__ __launch_bounds__(256)
void rowsum_kernel(const float* __restrict__ s_feats, float* __restrict__ rs)
{
    int t = blockIdx.x * 256 + threadIdx.x;
    int row = t >> 3;
    int l8  = t & 7;
    if (row >= MS) return;
    const float4* p = (const float4*)(s_feats + (size_t)row * CIN + l8 * 8);
    float4 a = p[0], b = p[1];
    float s = ((a.x + a.y) + (a.z + a.w)) + ((b.x + b.y) + (b.z + b.w));
    s += __shfl_xor(s, 1);
    s += __shfl_xor(s, 2);
    s += __shfl_xor(s, 4);
    if (l8 == 0) rs[row] = s;
}

// ---- helper 2: split W into bf16 hi/lo in B-fragment-linear layout ----
// B-frag (16x16x32 bf16): lane l holds B[k = kb*32 + (l>>4)*8 + j][n = t*16 + (l&15)], j=0..7.
// dst index = ((t*KBT + kb)*64 + lane)*8 + j  == tid (by construction).
__global__ __launch_bounds__(256)
void wsplit_kernel(const float* __restrict__ W, short* __restrict__ whi, short* __restrict__ wlo)
{
    int tid = blockIdx.x * 256 + threadIdx.x;
    if (tid >= NT * KBT * 64 * 8) return;        // 122880
    int j    = tid & 7;
    int lane = (tid >> 3) & 63;
    int kbt  = tid >> 9;
    int kb   = kbt % KBT;
    int t    = kbt / KBT;
    int row  = kb * 32 + ((lane >> 4) & 3) * 8 + j;
    int col  = t * 16 + (lane & 15);
    float x  = W[(size_t)row * COUT + col];
    short hi = f32_bf16(x);
    short lo = f32_bf16(x - bf16_f32(hi));
    whi[tid] = hi;
    wlo[tid] = lo;
}

// ---- main fused kernel (MFMA phase 2) ----
__global__ __launch_bounds__(256, 4)
void kpconv_mfma(const float* __restrict__ q_pts,
                 const float* __restrict__ s_pts,
                 const float* __restrict__ s_feats,
                 const int*   __restrict__ neigh,
                 const float* __restrict__ kpts,
                 const float* __restrict__ rowsum,
                 const short* __restrict__ whi,
                 const short* __restrict__ wlo,
                 float*       __restrict__ out)
{
    __shared__ __align__(16) float smem[QB * ASTR];   // 20736 B, unioned phase-1/phase-2
    __shared__ float norm_s[QB];

    float (*h_lds)[KNN][20] = (float (*)[KNN][20])smem;          // [4][32][20] = 2560 f
    float (*dxyz)[KNN][3]   = (float (*)[KNN][3])(smem + 2560);  // 384 f
    int*   idxl             = (int*)(smem + 2944);               // 128
    float* kp_s             = smem + 3072;                       // 45

    const int tid  = threadIdx.x;
    const int lane = tid & 63;
    const int wv   = tid >> 6;
    const int blk  = blockIdx.x;
    const int k32  = lane & 31;
    const int half = lane >> 5;

    if (tid < KP * 3) kp_s[tid] = kpts[tid];
    __syncthreads();

    float kfv[4][KP];   // wave's 4 queries, lane = input channel

    // ---------------- Phase 1: wave-per-query aggregation ----------------
    #pragma unroll
    for (int j = 0; j < 4; ++j) {
        const int q = wv * 4 + j;
        const int n = blk * QB + q;
        const float qx = q_pts[n * 3 + 0];
        const float qy = q_pts[n * 3 + 1];
        const float qz = q_pts[n * 3 + 2];

        bool flag = false;
        if (lane < KNN) {
            int idx = neigh[n * KNN + k32];
            idxl[wv * KNN + k32] = idx;
            bool valid = idx < MS;
            int  ic    = valid ? idx : MS - 1;
            float px = s_pts[ic * 3 + 0];
            float py = s_pts[ic * 3 + 1];
            float pz = s_pts[ic * 3 + 2];
            dxyz[wv][k32][0] = valid ? px - qx : 1e6f;
            dxyz[wv][k32][1] = valid ? py - qy : 1e6f;
            dxyz[wv][k32][2] = valid ? pz - qz : 1e6f;
            flag = valid && (rowsum[ic] > 0.0f);
        }
        {
            unsigned long long b = __ballot(flag);
            int cnt = (int)__popcll(b);
            if (lane == 0) norm_s[q] = 1.0f / (float)(cnt > 1 ? cnt : 1);
        }
        __builtin_amdgcn_wave_barrier();

        const float dx = dxyz[wv][k32][0];
        const float dy = dxyz[wv][k32][1];
        const float dz = dxyz[wv][k32][2];
        float om = 0.0f;
        #pragma unroll
        for (int p = 0; p < 8; ++p) {
            const int e = (p << 1) + half;
            if (e < KP) {
                float ax = dx - kp_s[e * 3 + 0];
                float ay = dy - kp_s[e * 3 + 1];
                float az = dz - kp_s[e * 3 + 2];
                float d2 = ax * ax + ay * ay + az * az + 1e-8f;
                float hh = 1.0f - sqrtf(d2) * KP_EXT_INV;
                hh = hh > 0.0f ? hh : 0.0f;
                h_lds[wv][k32][e] = hh;
                om = fmaxf(om, hh);
            }
        }
        om = fmaxf(om, __shfl_xor(om, 32));
        unsigned long long bh = __ballot(om > 0.0f);
        unsigned int kmask = (unsigned int)bh;
        __builtin_amdgcn_wave_barrier();

        #pragma unroll
        for (int e = 0; e < KP; ++e) kfv[j][e] = 0.0f;
        unsigned int mk = kmask;
        while (mk) {
            int k = __builtin_ctz(mk);
            mk &= mk - 1;
            int idx2 = idxl[wv * KNN + k];
            int ic2  = idx2 < MS ? idx2 : MS - 1;
            float nf = s_feats[(size_t)ic2 * CIN + lane];
            const float4* hr = (const float4*)(&h_lds[wv][k][0]);
            float4 h0 = hr[0], h1 = hr[1], h2 = hr[2], h3 = hr[3];
            kfv[j][0]  += h0.x * nf;  kfv[j][1]  += h0.y * nf;
            kfv[j][2]  += h0.z * nf;  kfv[j][3]  += h0.w * nf;
            kfv[j][4]  += h1.x * nf;  kfv[j][5]  += h1.y * nf;
            kfv[j][6]  += h1.z * nf;  kfv[j][7]  += h1.w * nf;
            kfv[j][8]  += h2.x * nf;  kfv[j][9]  += h2.y * nf;
            kfv[j][10] += h2.z * nf;  kfv[j][11] += h2.w * nf;
            kfv[j][12] += h3.x * nf;  kfv[j][13] += h3.y * nf;
            kfv[j][14] += h3.z * nf;
        }
    }

    // ---------------- Phase 2: split-bf16 MFMA GEMM ----------------
    // D[q=0..15][o] = sum_k kf[q][k] * W[k][o]; 3 rounds of 5 kernel points.
    const int qA   = lane & 15;      // A-frag m index
    const int quad = lane >> 4;
    const int t0 = 2 * wv, t1 = 2 * wv + 1;   // this wave's two n-tiles

    f32x4 acc0 = {0.f, 0.f, 0.f, 0.f};
    f32x4 acc1 = {0.f, 0.f, 0.f, 0.f};

    const short8* wh = (const short8*)whi;
    const short8* wl = (const short8*)wlo;

    #pragma unroll
    for (int r = 0; r < RND; ++r) {
        __syncthreads();             // all waves past phase-1 / prior round reads
        // dump kf chunk in A-read order: row q' = 4*wv+j, col i = e5*64 + lane
        #pragma unroll
        for (int j = 0; j < 4; ++j) {
            #pragma unroll
            for (int e5 = 0; e5 < RE; ++e5) {
                smem[(4 * wv + j) * ASTR + e5 * CIN + lane] = kfv[j][r * RE + e5];
            }
        }
        __syncthreads();

        #pragma unroll 2
        for (int kb = 0; kb < KBR; ++kb) {
            // A-frag: 8 consecutive f32 kf[qA][kb*32 + quad*8 + j]
            const float4* ap = (const float4*)(smem + qA * ASTR + kb * 32 + quad * 8);
            float4 a01 = ap[0], a23 = ap[1];
            float av[8] = {a01.x, a01.y, a01.z, a01.w, a23.x, a23.y, a23.z, a23.w};
            short8 ahi, alo;
            #pragma unroll
            for (int u = 0; u < 8; ++u) {
                short hi = f32_bf16(av[u]);
                ahi[u] = hi;
                alo[u] = f32_bf16(av[u] - bf16_f32(hi));
            }
            const int kbg = r * KBR + kb;
            short8 b0h = wh[(t0 * KBT + kbg) * 64 + lane];
            short8 b0l = wl[(t0 * KBT + kbg) * 64 + lane];
            short8 b1h = wh[(t1 * KBT + kbg) * 64 + lane];
            short8 b1l = wl[(t1 * KBT + kbg) * 64 + lane];

            acc0 = __builtin_amdgcn_mfma_f32_16x16x32_bf16(ahi, b0h, acc0, 0, 0, 0);
            acc0 = __builtin_amdgcn_mfma_f32_16x16x32_bf16(ahi, b0l, acc0, 0, 0, 0);
            acc0 = __builtin_amdgcn_mfma_f32_16x16x32_bf16(alo, b0h, acc0, 0, 0, 0);
            acc1 = __builtin_amdgcn_mfma_f32_16x16x32_bf16(ahi, b1h, acc1, 0, 0, 0);
            acc1 = __builtin_amdgcn_mfma_f32_16x16x32_bf16(ahi, b1l, acc1, 0, 0, 0);
            acc1 = __builtin_amdgcn_mfma_f32_16x16x32_bf16(alo, b1h, acc1, 0, 0, 0);
        }
    }

    // epilogue: D row m = quad*4+reg (query), col n = lane&15 (output within tile)
    const int oc = lane & 15;
    #pragma unroll
    for (int rr = 0; rr < 4; ++rr) {
        int qm = quad * 4 + rr;
        float nm = norm_s[qm];
        size_t rowb = (size_t)(blk * QB + qm) * COUT;
        out[rowb + t0 * 16 + oc] = acc0[rr] * nm;
        out[rowb + t1 * 16 + oc] = acc1[rr] * nm;
    }
}

// ---- fallback (R2 path, no workspace requirement) ----
__global__ __launch_bounds__(256, 6)
void kpconv_fallback(const float* __restrict__ q_pts,
                     const float* __restrict__ s_pts,
                     const float* __restrict__ s_feats,
                     const int*   __restrict__ neigh,
                     const float* __restrict__ W,
                     const float* __restrict__ kpts,
                     float*       __restrict__ out)
{
    constexpr int CHUNK_I = 320, NPAIR = 160;
    __shared__ __align__(16) float smem[NPAIR * 32];
    __shared__ float norm_s[QB];
    float (*h_lds)[KNN][20] = (float (*)[KNN][20])smem;
    float (*dxyz)[KNN][3]   = (float (*)[KNN][3])(smem + 2560);
    int*   idxl             = (int*)(smem + 2944);
    float* kp_s             = smem + 3072;

    const int tid = threadIdx.x, lane = tid & 63, wv = tid >> 6, blk = blockIdx.x;
    const int k32 = lane & 31, half = lane >> 5;
    if (tid < KP * 3) kp_s[tid] = kpts[tid];
    __syncthreads();
    float kfv[4][KP];

    #pragma unroll
    for (int j = 0; j < 4; ++j) {
        const int q = wv * 4 + j, n = blk * QB + q;
        const float qx = q_pts[n*3], qy = q_pts[n*3+1], qz = q_pts[n*3+2];
        if (lane < KNN) {
            int idx = neigh[n * KNN + k32];
            idxl[wv * KNN + k32] = idx;
            bool valid = idx < MS;
            int ic = valid ? idx : MS - 1;
            dxyz[wv][k32][0] = valid ? s_pts[ic*3]   - qx : 1e6f;
            dxyz[wv][k32][1] = valid ? s_pts[ic*3+1] - qy : 1e6f;
            dxyz[wv][k32][2] = valid ? s_pts[ic*3+2] - qz : 1e6f;
        }
        __builtin_amdgcn_wave_barrier();
        const float dx = dxyz[wv][k32][0], dy = dxyz[wv][k32][1], dz = dxyz[wv][k32][2];
        float om = 0.0f;
        #pragma unroll
        for (int p = 0; p < 8; ++p) {
            const int e = (p << 1) + half;
            if (e < KP) {
                float ax = dx - kp_s[e*3], ay = dy - kp_s[e*3+1], az = dz - kp_s[e*3+2];
                float hh = 1.0f - sqrtf(ax*ax + ay*ay + az*az + 1e-8f) * KP_EXT_INV;
                hh = hh > 0.0f ? hh : 0.0f;
                h_lds[wv][k32][e] = hh;
                om = fmaxf(om, hh);
            }
        }
        om = fmaxf(om, __shfl_xor(om, 32));
        unsigned int kmask = (unsigned int)__ballot(om > 0.0f);
        __builtin_amdgcn_wave_barrier();
        {
            int idx = idxl[wv * KNN + k32];
            bool valid = idx < MS;
            int ic = valid ? idx : MS - 1;
            const float4* rp = (const float4*)(s_feats + (size_t)ic * CIN + half * 32);
            float4 s4 = rp[0];
            #pragma unroll
            for (int t = 1; t < 8; ++t) { float4 a = rp[t]; s4.x+=a.x; s4.y+=a.y; s4.z+=a.z; s4.w+=a.w; }
            float s = (s4.x + s4.y) + (s4.z + s4.w);
            s += __shfl_xor(s, 32);
            unsigned long long b = __ballot(valid && (s > 0.0f));
            int cnt = (int)(__popcll(b) >> 1);
            if (lane == 0) norm_s[q] = 1.0f / (float)(cnt > 1 ? cnt : 1);
        }
        #pragma unroll
        for (int e = 0; e < KP; ++e) kfv[j][e] = 0.0f;
        unsigned int mk = kmask;
        while (mk) {
            int k = __builtin_ctz(mk); mk &= mk - 1;
            int idx2 = idxl[wv * KNN + k];
            int ic2 = idx2 < MS ? idx2 : MS - 1;
            float nf = s_feats[(size_t)ic2 * CIN + lane];
            const float4* hr = (const float4*)(&h_lds[wv][k][0]);
            float4 h0 = hr[0], h1 = hr[1], h2 = hr[2], h3 = hr[3];
            kfv[j][0]+=h0.x*nf; kfv[j][1]+=h0.y*nf; kfv[j][2]+=h0.z*nf; kfv[j][3]+=h0.w*nf;
            kfv[j][4]+=h1.x*nf; kfv[j][5]+=h1.y*nf; kfv[j][6]+=h1.z*nf; kfv[j][7]+=h1.w*nf;
            kfv[j][8]+=h2.x*nf; kfv[j][9]+=h2.y*nf; kfv[j][10]+=h2.z*nf; kfv[j][11]+=h2.w*nf;
            kfv[j][12]+=h3.x*nf; kfv[j][13]+=h3.y*nf; kfv[j][14]+=h3.z*nf;
        }
    }

    const int o4 = tid & 31, qi = tid >> 5, q0 = qi * 2, q1 = q0 + 1;
    float4 tot0 = make_float4(0,0,0,0), tot1 = make_float4(0,0,0,0);
    #pragma unroll
    for (int r = 0; r < 3; ++r) {
        __syncthreads();
        #pragma unroll
        for (int j = 0; j < 4; ++j) {
            const int q = wv * 4 + j;
            #pragma unroll
            for (int e5 = 0; e5 < 5; ++e5) {
                int i = e5 * CIN + lane, pr = i >> 1, m = pr & 14;
                smem[pr * 32 + ((q ^ m) << 1) + (i & 1)] = kfv[j][r * 5 + e5];
            }
        }
        __syncthreads();
        const float* wb = W + (size_t)(r * CHUNK_I) * COUT + (o4 << 2);
        float4 acc0 = make_float4(0,0,0,0), acc1 = make_float4(0,0,0,0);
        #pragma unroll 4
        for (int p = 0; p < NPAIR; ++p) {
            float4 kk = *(const float4*)(smem + p * 32 + ((q0 ^ (p & 14)) << 1));
            float4 w0 = *(const float4*)(wb + (size_t)(2*p) * COUT);
            float4 w1 = *(const float4*)(wb + (size_t)(2*p+1) * COUT);
            acc0.x+=w0.x*kk.x; acc0.y+=w0.y*kk.x; acc0.z+=w0.z*kk.x; acc0.w+=w0.w*kk.x;
            acc1.x+=w0.x*kk.z; acc1.y+=w0.y*kk.z; acc1.z+=w0.z*kk.z; acc1.w+=w0.w*kk.z;
            acc0.x+=w1.x*kk.y; acc0.y+=w1.y*kk.y; acc0.z+=w1.z*kk.y; acc0.w+=w1.w*kk.y;
            acc1.x+=w1.x*kk.w; acc1.y+=w1.y*kk.w; acc1.z+=w1.z*kk.w; acc1.w+=w1.w*kk.w;
        }
        tot0.x+=acc0.x; tot0.y+=acc0.y; tot0.z+=acc0.z; tot0.w+=acc0.w;
        tot1.x+=acc1.x; tot1.y+=acc1.y; tot1.z+=acc1.z; tot1.w+=acc1.w;
    }
    const float nm0 = norm_s[q0], nm1 = norm_s[q1];
    const size_t base = (size_t)(blk * QB) * COUT + (o4 << 2);
    *(float4*)(out + base + (size_t)q0 * COUT) =
        make_float4(tot0.x*nm0, tot0.y*nm0, tot0.z*nm0, tot0.w*nm0);
    *(float4*)(out + base + (size_t)q1 * COUT) =
        make_float4(tot1.x*nm1, tot1.y*nm1, tot1.z*nm1, tot1.w*nm1);
}

extern "C" void kernel_launch(void* const* d_in, const int* in_sizes, int n_in,
                              void* d_out, int out_size, void* d_ws, size_t ws_size,
                              hipStream_t stream) {
    const float* q_pts   = (const float*)d_in[0];
    const float* s_pts   = (const float*)d_in[1];
    const float* s_feats = (const float*)d_in[2];
    const int*   neigh   = (const int*)d_in[3];
    const float* W       = (const float*)d_in[4];
    const float* kpts    = (const float*)d_in[5];
    float* outp = (float*)d_out;

    dim3 grid(NQ / QB);   // 3125
    dim3 block(256);

    if (ws_size >= WS_NEED) {
        float* rs  = (float*)d_ws;
        short* whi = (short*)((char*)d_ws + WS_HI);
        short* wlo = (short*)((char*)d_ws + WS_LO);
        int rs_blocks = (MS * 8 + 255) / 256;
        hipLaunchKernelGGL(rowsum_kernel, dim3(rs_blocks), dim3(256), 0, stream, s_feats, rs);
        hipLaunchKernelGGL(wsplit_kernel, dim3((NT * KBT * 64 * 8 + 255) / 256), dim3(256),
                           0, stream, W, whi, wlo);
        hipLaunchKernelGGL(kpconv_mfma, grid, block, 0, stream,
                           q_pts, s_pts, s_feats, neigh, kpts, rs, whi, wlo, outp);
    } else {
        hipLaunchKernelGGL(kpconv_fallback, grid, block, 0, stream,
                           q_pts, s_pts, s_feats, neigh, W, kpts, outp);
    }
}

// Round 4
// 163.800 us; speedup vs baseline: 4.0065x; 1.0565x over previous
//
#include <hip/hip_runtime.h>

// KPConv fused, R4.
//  - QB=32 queries/block, 512 threads (8 waves). Wave w owns n-tile w and computes
//    BOTH m-tiles -> W(hi/lo) read once per block: L2 traffic halved vs R3.
//  - Phase 1d: valid-k compacted into LDS list (pads point at a zeroed h-row),
//    chunk-4 prefetched gathers with scalar (readfirstlane) row bases.
//  - kf dumped to LDS as packed (bf16hi<<16)|bf16lo; A-frags unpacked with v_perm.
//  - rowsum + W-split fused into one prep kernel (2 launches total).

namespace {
constexpr int NQ   = 50000;
constexpr int MS   = 50000;
constexpr int KNN  = 32;
constexpr int KP   = 15;
constexpr int CIN  = 64;
constexpr int COUT = 128;
constexpr int QB   = 32;                 // queries per block (2 MFMA m-tiles)
constexpr int ROWS = KP * CIN;           // 960
constexpr int RND  = 3;
constexpr int RE   = 5;                  // kernel points per round
constexpr int KBR  = (RE * CIN) / 32;    // 10 k-blocks per round
constexpr int KBT  = ROWS / 32;          // 30 k-blocks total
constexpr int NT   = COUT / 16;          // 8 n-tiles
constexpr int ASTR = RE * CIN + 4;       // 324 dwords per kf row
constexpr float KP_EXT_INV = 1.0f / 1.2f;
constexpr size_t WS_HI   = 200704;
constexpr size_t WS_LO   = WS_HI + (size_t)ROWS * COUT * 2;   // 446464
constexpr size_t WS_NEED = WS_LO + (size_t)ROWS * COUT * 2;   // 692224
// phase-1 float offsets inside the 32*324-dword union
constexpr int OF_H   = 0;      // 8 waves * 33 rows * 20 = 5280
constexpr int OF_DX  = 5280;   // 8 * 32 * 3 = 768
constexpr int OF_CPK = 6048;   // 8 * 32 ints = 256
constexpr int OF_KP  = 6304;   // 45
}

typedef __attribute__((ext_vector_type(8))) short short8;
typedef __attribute__((ext_vector_type(4))) float f32x4;
typedef __attribute__((ext_vector_type(4))) unsigned int u32x4;

__device__ __forceinline__ short f32_bf16(float x) {
    unsigned u = __builtin_bit_cast(unsigned, x);
    u = u + 0x7fffu + ((u >> 16) & 1u);
    return (short)(u >> 16);
}
__device__ __forceinline__ float bf16_f32(short h) {
    unsigned u = ((unsigned)(unsigned short)h) << 16;
    return __builtin_bit_cast(float, u);
}
__device__ __forceinline__ unsigned pack_hilo(float x) {
    unsigned xu = __builtin_bit_cast(unsigned, x);
    unsigned r  = xu + 0x7fffu + ((xu >> 16) & 1u);
    unsigned hi = r & 0xffff0000u;
    float lof = x - __builtin_bit_cast(float, hi);
    unsigned lu = __builtin_bit_cast(unsigned, lof);
    unsigned r2 = lu + 0x7fffu + ((lu >> 16) & 1u);
    return hi | (r2 >> 16);
}
__device__ __forceinline__ unsigned permb(unsigned a, unsigned b, unsigned sel) {
#if __has_builtin(__builtin_amdgcn_perm)
    return __builtin_amdgcn_perm(a, b, sel);
#else
    // fallback: byte-select emulation for the two selectors we use
    if (sel == 0x07060302u) return (a & 0xffff0000u) | (b >> 16);
    return (a << 16) | (b & 0xffffu);
#endif
}
// 8 packed uints (two uint4) -> bf16-hi short8 and bf16-lo short8
__device__ __forceinline__ void unpack_a(uint4 a, uint4 b, short8& hi, short8& lo) {
    u32x4 h, l;
    h[0] = permb(a.y, a.x, 0x07060302u); l[0] = permb(a.y, a.x, 0x05040100u);
    h[1] = permb(a.w, a.z, 0x07060302u); l[1] = permb(a.w, a.z, 0x05040100u);
    h[2] = permb(b.y, b.x, 0x07060302u); l[2] = permb(b.y, b.x, 0x05040100u);
    h[3] = permb(b.w, b.z, 0x07060302u); l[3] = permb(b.w, b.z, 0x05040100u);
    hi = __builtin_bit_cast(short8, h);
    lo = __builtin_bit_cast(short8, l);
}

// ---- prep: rowsum (blocks >= 60) + W split into B-frag layout (blocks < 60) ----
__global__ __launch_bounds__(256)
void prep_kernel(const float* __restrict__ s_feats, const float* __restrict__ W,
                 float* __restrict__ rs, short* __restrict__ whi, short* __restrict__ wlo)
{
    int b = blockIdx.x;
    if (b < 60) {
        int wv = threadIdx.x >> 6, lane = threadIdx.x & 63;
        int id = b * 4 + wv;                    // (t,kb) pair, 0..239
        int t = id / KBT, kb = id % KBT;
        short8 hi8, lo8;
        #pragma unroll
        for (int j = 0; j < 8; ++j) {
            int row = kb * 32 + ((lane >> 4) & 3) * 8 + j;
            int col = t * 16 + (lane & 15);
            float x = W[(size_t)row * COUT + col];
            short h = f32_bf16(x);
            hi8[j] = h;
            lo8[j] = f32_bf16(x - bf16_f32(h));
        }
        ((short8*)whi)[id * 64 + lane] = hi8;
        ((short8*)wlo)[id * 64 + lane] = lo8;
    } else {
        int tdx = (b - 60) * 256 + threadIdx.x;
        int row = tdx >> 3, l8 = tdx & 7;
        if (row < MS) {
            const float4* p = (const float4*)(s_feats + (size_t)row * CIN + l8 * 8);
            float4 a = p[0], c = p[1];
            float s = ((a.x + a.y) + (a.z + a.w)) + ((c.x + c.y) + (c.z + c.w));
            s += __shfl_xor(s, 1);
            s += __shfl_xor(s, 2);
            s += __shfl_xor(s, 4);
            if (l8 == 0) rs[row] = s;
        }
    }
}

// ---- main fused kernel ----
__global__ __launch_bounds__(512, 4)
void kpconv_mfma(const float* __restrict__ q_pts,
                 const float* __restrict__ s_pts,
                 const float* __restrict__ s_feats,
                 const int*   __restrict__ neigh,
                 const float* __restrict__ kpts,
                 const float* __restrict__ rowsum,
                 const short* __restrict__ whi,
                 const short* __restrict__ wlo,
                 float*       __restrict__ out)
{
    __shared__ __align__(16) unsigned int smem[QB * ASTR];   // 41472 B union
    __shared__ float norm_s[QB];

    float* smf   = (float*)smem;
    const int tid  = threadIdx.x;
    const int lane = tid & 63;
    const int wv   = tid >> 6;       // 0..7
    const int blk  = blockIdx.x;
    const int k32  = lane & 31;
    const int half = lane >> 5;
    const int quad = lane >> 4;

    float* hbase = smf + OF_H + wv * 660;           // 33 rows x 20 (row 32 = zero pad)
    float* dx_b  = smf + OF_DX + wv * 96;
    int*   cpk   = (int*)(smf + OF_CPK) + wv * 32;
    float* kp_s  = smf + OF_KP;

    if (tid < KP * 3) kp_s[tid] = kpts[tid];
    if (lane < 20) hbase[640 + lane] = 0.0f;        // zero h-row for pads
    __syncthreads();

    float kfv[4][KP];

    // ---------------- Phase 1 ----------------
    #pragma unroll
    for (int j = 0; j < 4; ++j) {
        const int q  = wv * 4 + j;
        const int n  = blk * QB + q;
        const int nc = n < NQ ? n : NQ - 1;          // tail-block clamp
        const float qx = q_pts[nc * 3 + 0];
        const float qy = q_pts[nc * 3 + 1];
        const float qz = q_pts[nc * 3 + 2];

        int idx = MS;
        bool flag = false;
        if (lane < KNN) {
            idx = neigh[nc * KNN + k32];
            bool valid = idx < MS;
            int  ic    = valid ? idx : MS - 1;
            float px = s_pts[ic * 3 + 0];
            float py = s_pts[ic * 3 + 1];
            float pz = s_pts[ic * 3 + 2];
            dx_b[k32 * 3 + 0] = valid ? px - qx : 1e6f;
            dx_b[k32 * 3 + 1] = valid ? py - qy : 1e6f;
            dx_b[k32 * 3 + 2] = valid ? pz - qz : 1e6f;
            flag = valid && (rowsum[ic] > 0.0f);
        }
        {
            unsigned long long b = __ballot(flag);
            int cnt = (int)__popcll(b);
            if (lane == 0) norm_s[q] = 1.0f / (float)(cnt > 1 ? cnt : 1);
        }
        __builtin_amdgcn_wave_barrier();

        const float dx = dx_b[k32 * 3 + 0];
        const float dy = dx_b[k32 * 3 + 1];
        const float dz = dx_b[k32 * 3 + 2];
        float om = 0.0f;
        #pragma unroll
        for (int p = 0; p < 8; ++p) {
            const int e = (p << 1) + half;
            if (e < KP) {
                float ax = dx - kp_s[e * 3 + 0];
                float ay = dy - kp_s[e * 3 + 1];
                float az = dz - kp_s[e * 3 + 2];
                float d2 = ax * ax + ay * ay + az * az + 1e-8f;
                float hh = 1.0f - sqrtf(d2) * KP_EXT_INV;
                hh = hh > 0.0f ? hh : 0.0f;
                hbase[k32 * 20 + e] = hh;
                om = fmaxf(om, hh);
            }
        }
        om = fmaxf(om, __shfl_xor(om, 32));
        unsigned int kmask = (unsigned int)__ballot(om > 0.0f);
        int nv = __popc(kmask);

        // compaction: set bits -> slots [0,nv), clear bits -> pads [nv,32)
        if (lane < KNN) {
            bool bit = (kmask >> k32) & 1u;
            int pos = bit ? __popc(kmask & ((1u << k32) - 1u))
                          : nv + __popc((~kmask) & ((1u << k32) - 1u));
            cpk[pos] = bit ? ((idx << 6) | k32) : 32;   // pad: row 0, h-row 32 (zero)
        }
        __builtin_amdgcn_wave_barrier();

        #pragma unroll
        for (int e = 0; e < KP; ++e) kfv[j][e] = 0.0f;
        const int nvr = (nv + 3) & ~3;
        for (int base = 0; base < nvr; base += 4) {
            int pk[4];
            float nf[4];
            #pragma unroll
            for (int u = 0; u < 4; ++u) pk[u] = __builtin_amdgcn_readfirstlane(cpk[base + u]);
            #pragma unroll
            for (int u = 0; u < 4; ++u) nf[u] = s_feats[(size_t)(pk[u] >> 6) * CIN + lane];
            #pragma unroll
            for (int u = 0; u < 4; ++u) {
                const float4* hr = (const float4*)(hbase + (pk[u] & 63) * 20);
                float4 h0 = hr[0], h1 = hr[1], h2 = hr[2], h3 = hr[3];
                float f = nf[u];
                kfv[j][0]  += h0.x * f;  kfv[j][1]  += h0.y * f;
                kfv[j][2]  += h0.z * f;  kfv[j][3]  += h0.w * f;
                kfv[j][4]  += h1.x * f;  kfv[j][5]  += h1.y * f;
                kfv[j][6]  += h1.z * f;  kfv[j][7]  += h1.w * f;
                kfv[j][8]  += h2.x * f;  kfv[j][9]  += h2.y * f;
                kfv[j][10] += h2.z * f;  kfv[j][11] += h2.w * f;
                kfv[j][12] += h3.x * f;  kfv[j][13] += h3.y * f;
                kfv[j][14] += h3.z * f;
            }
        }
    }

    // ---------------- Phase 2: split-bf16 MFMA, wave = n-tile, both m-tiles ----------------
    const short8* wh = (const short8*)whi;
    const short8* wl = (const short8*)wlo;
    f32x4 acc0 = {0.f, 0.f, 0.f, 0.f};   // m-tile 0 (queries 0..15)
    f32x4 acc1 = {0.f, 0.f, 0.f, 0.f};   // m-tile 1 (queries 16..31)
    const int qA = lane & 15;

    #pragma unroll
    for (int r = 0; r < RND; ++r) {
        __syncthreads();                 // all waves done with phase-1 / prior reads
        #pragma unroll
        for (int j = 0; j < 4; ++j) {
            const int q = wv * 4 + j;
            #pragma unroll
            for (int e5 = 0; e5 < RE; ++e5) {
                smem[q * ASTR + e5 * CIN + lane] = pack_hilo(kfv[j][r * RE + e5]);
            }
        }
        __syncthreads();

        #pragma unroll 2
        for (int kb = 0; kb < KBR; ++kb) {
            const uint4* a0p = (const uint4*)(smem + qA * ASTR + kb * 32 + quad * 8);
            uint4 a0 = a0p[0], a0b = a0p[1];
            const uint4* a1p = (const uint4*)(smem + (16 + qA) * ASTR + kb * 32 + quad * 8);
            uint4 a1 = a1p[0], a1b = a1p[1];
            short8 ah0, al0, ah1, al1;
            unpack_a(a0, a0b, ah0, al0);
            unpack_a(a1, a1b, ah1, al1);

            const int kbg = r * KBR + kb;
            short8 bh = wh[(wv * KBT + kbg) * 64 + lane];
            short8 bl = wl[(wv * KBT + kbg) * 64 + lane];

            acc0 = __builtin_amdgcn_mfma_f32_16x16x32_bf16(ah0, bh, acc0, 0, 0, 0);
            acc1 = __builtin_amdgcn_mfma_f32_16x16x32_bf16(ah1, bh, acc1, 0, 0, 0);
            acc0 = __builtin_amdgcn_mfma_f32_16x16x32_bf16(ah0, bl, acc0, 0, 0, 0);
            acc1 = __builtin_amdgcn_mfma_f32_16x16x32_bf16(ah1, bl, acc1, 0, 0, 0);
            acc0 = __builtin_amdgcn_mfma_f32_16x16x32_bf16(al0, bh, acc0, 0, 0, 0);
            acc1 = __builtin_amdgcn_mfma_f32_16x16x32_bf16(al1, bh, acc1, 0, 0, 0);
        }
    }

    // epilogue: D row m = quad*4+rr (query within tile), col = lane&15
    const int oc = lane & 15;
    #pragma unroll
    for (int rr = 0; rr < 4; ++rr) {
        int qm0 = quad * 4 + rr;
        int qm1 = 16 + qm0;
        int n0 = blk * QB + qm0;
        int n1 = blk * QB + qm1;
        if (n0 < NQ) out[(size_t)n0 * COUT + wv * 16 + oc] = acc0[rr] * norm_s[qm0];
        if (n1 < NQ) out[(size_t)n1 * COUT + wv * 16 + oc] = acc1[rr] * norm_s[qm1];
    }
}

// ---- fallback (QB=16, no-workspace path; R3-verified) ----
__global__ __launch_bounds__(256, 6)
void kpconv_fallback(const float* __restrict__ q_pts,
                     const float* __restrict__ s_pts,
                     const float* __restrict__ s_feats,
                     const int*   __restrict__ neigh,
                     const float* __restrict__ W,
                     const float* __restrict__ kpts,
                     float*       __restrict__ out)
{
    constexpr int QBF = 16, CHUNK_I = 320, NPAIR = 160;
    __shared__ __align__(16) float smem[NPAIR * 32];
    __shared__ float norm_s[QBF];
    float (*h_lds)[KNN][20] = (float (*)[KNN][20])smem;
    float (*dxyz)[KNN][3]   = (float (*)[KNN][3])(smem + 2560);
    int*   idxl             = (int*)(smem + 2944);
    float* kp_s             = smem + 3072;

    const int tid = threadIdx.x, lane = tid & 63, wv = tid >> 6, blk = blockIdx.x;
    const int k32 = lane & 31, half = lane >> 5;
    if (tid < KP * 3) kp_s[tid] = kpts[tid];
    __syncthreads();
    float kfv[4][KP];

    #pragma unroll
    for (int j = 0; j < 4; ++j) {
        const int q = wv * 4 + j, n = blk * QBF + q;
        const float qx = q_pts[n*3], qy = q_pts[n*3+1], qz = q_pts[n*3+2];
        if (lane < KNN) {
            int idx = neigh[n * KNN + k32];
            idxl[wv * KNN + k32] = idx;
            bool valid = idx < MS;
            int ic = valid ? idx : MS - 1;
            dxyz[wv][k32][0] = valid ? s_pts[ic*3]   - qx : 1e6f;
            dxyz[wv][k32][1] = valid ? s_pts[ic*3+1] - qy : 1e6f;
            dxyz[wv][k32][2] = valid ? s_pts[ic*3+2] - qz : 1e6f;
        }
        __builtin_amdgcn_wave_barrier();
        const float dx = dxyz[wv][k32][0], dy = dxyz[wv][k32][1], dz = dxyz[wv][k32][2];
        float om = 0.0f;
        #pragma unroll
        for (int p = 0; p < 8; ++p) {
            const int e = (p << 1) + half;
            if (e < KP) {
                float ax = dx - kp_s[e*3], ay = dy - kp_s[e*3+1], az = dz - kp_s[e*3+2];
                float hh = 1.0f - sqrtf(ax*ax + ay*ay + az*az + 1e-8f) * KP_EXT_INV;
                hh = hh > 0.0f ? hh : 0.0f;
                h_lds[wv][k32][e] = hh;
                om = fmaxf(om, hh);
            }
        }
        om = fmaxf(om, __shfl_xor(om, 32));
        unsigned int kmask = (unsigned int)__ballot(om > 0.0f);
        __builtin_amdgcn_wave_barrier();
        {
            int idx = idxl[wv * KNN + k32];
            bool valid = idx < MS;
            int ic = valid ? idx : MS - 1;
            const float4* rp = (const float4*)(s_feats + (size_t)ic * CIN + half * 32);
            float4 s4 = rp[0];
            #pragma unroll
            for (int t = 1; t < 8; ++t) { float4 a = rp[t]; s4.x+=a.x; s4.y+=a.y; s4.z+=a.z; s4.w+=a.w; }
            float s = (s4.x + s4.y) + (s4.z + s4.w);
            s += __shfl_xor(s, 32);
            unsigned long long b = __ballot(valid && (s > 0.0f));
            int cnt = (int)(__popcll(b) >> 1);
            if (lane == 0) norm_s[q] = 1.0f / (float)(cnt > 1 ? cnt : 1);
        }
        #pragma unroll
        for (int e = 0; e < KP; ++e) kfv[j][e] = 0.0f;
        unsigned int mk = kmask;
        while (mk) {
            int k = __builtin_ctz(mk); mk &= mk - 1;
            int idx2 = idxl[wv * KNN + k];
            int ic2 = idx2 < MS ? idx2 : MS - 1;
            float nf = s_feats[(size_t)ic2 * CIN + lane];
            const float4* hr = (const float4*)(&h_lds[wv][k][0]);
            float4 h0 = hr[0], h1 = hr[1], h2 = hr[2], h3 = hr[3];
            kfv[j][0]+=h0.x*nf; kfv[j][1]+=h0.y*nf; kfv[j][2]+=h0.z*nf; kfv[j][3]+=h0.w*nf;
            kfv[j][4]+=h1.x*nf; kfv[j][5]+=h1.y*nf; kfv[j][6]+=h1.z*nf; kfv[j][7]+=h1.w*nf;
            kfv[j][8]+=h2.x*nf; kfv[j][9]+=h2.y*nf; kfv[j][10]+=h2.z*nf; kfv[j][11]+=h2.w*nf;
            kfv[j][12]+=h3.x*nf; kfv[j][13]+=h3.y*nf; kfv[j][14]+=h3.z*nf;
        }
    }

    const int o4 = tid & 31, qi = tid >> 5, q0 = qi * 2, q1 = q0 + 1;
    float4 tot0 = make_float4(0,0,0,0), tot1 = make_float4(0,0,0,0);
    #pragma unroll
    for (int r = 0; r < 3; ++r) {
        __syncthreads();
        #pragma unroll
        for (int j = 0; j < 4; ++j) {
            const int q = wv * 4 + j;
            #pragma unroll
            for (int e5 = 0; e5 < 5; ++e5) {
                int i = e5 * CIN + lane, pr = i >> 1, m = pr & 14;
                smem[pr * 32 + ((q ^ m) << 1) + (i & 1)] = kfv[j][r * 5 + e5];
            }
        }
        __syncthreads();
        const float* wb = W + (size_t)(r * CHUNK_I) * COUT + (o4 << 2);
        float4 acc0 = make_float4(0,0,0,0), acc1 = make_float4(0,0,0,0);
        #pragma unroll 4
        for (int p = 0; p < NPAIR; ++p) {
            float4 kk = *(const float4*)(smem + p * 32 + ((q0 ^ (p & 14)) << 1));
            float4 w0 = *(const float4*)(wb + (size_t)(2*p) * COUT);
            float4 w1 = *(const float4*)(wb + (size_t)(2*p+1) * COUT);
            acc0.x+=w0.x*kk.x; acc0.y+=w0.y*kk.x; acc0.z+=w0.z*kk.x; acc0.w+=w0.w*kk.x;
            acc1.x+=w0.x*kk.z; acc1.y+=w0.y*kk.z; acc1.z+=w0.z*kk.z; acc1.w+=w0.w*kk.z;
            acc0.x+=w1.x*kk.y; acc0.y+=w1.y*kk.y; acc0.z+=w1.z*kk.y; acc0.w+=w1.w*kk.y;
            acc1.x+=w1.x*kk.w; acc1.y+=w1.y*kk.w; acc1.z+=w1.z*kk.w; acc1.w+=w1.w*kk.w;
        }
        tot0.x+=acc0.x; tot0.y+=acc0.y; tot0.z+=acc0.z; tot0.w+=acc0.w;
        tot1.x+=acc1.x; tot1.y+=acc1.y; tot1.z+=acc1.z; tot1.w+=acc1.w;
    }
    const float nm0 = norm_s[q0], nm1 = norm_s[q1];
    const size_t base = (size_t)(blk * QBF) * COUT + (o4 << 2);
    *(float4*)(out + base + (size_t)q0 * COUT) =
        make_float4(tot0.x*nm0, tot0.y*nm0, tot0.z*nm0, tot0.w*nm0);
    *(float4*)(out + base + (size_t)q1 * COUT) =
        make_float4(tot1.x*nm1, tot1.y*nm1, tot1.z*nm1, tot1.w*nm1);
}

extern "C" void kernel_launch(void* const* d_in, const int* in_sizes, int n_in,
                              void* d_out, int out_size, void* d_ws, size_t ws_size,
                              hipStream_t stream) {
    const float* q_pts   = (const float*)d_in[0];
    const float* s_pts   = (const float*)d_in[1];
    const float* s_feats = (const float*)d_in[2];
    const int*   neigh   = (const int*)d_in[3];
    const float* W       = (const float*)d_in[4];
    const float* kpts    = (const float*)d_in[5];
    float* outp = (float*)d_out;

    if (ws_size >= WS_NEED) {
        float* rs  = (float*)d_ws;
        short* whi = (short*)((char*)d_ws + WS_HI);
        short* wlo = (short*)((char*)d_ws + WS_LO);
        int rs_blocks = (MS * 8 + 255) / 256;       // 1563
        hipLaunchKernelGGL(prep_kernel, dim3(60 + rs_blocks), dim3(256), 0, stream,
                           s_feats, W, rs, whi, wlo);
        hipLaunchKernelGGL(kpconv_mfma, dim3((NQ + QB - 1) / QB), dim3(512), 0, stream,
                           q_pts, s_pts, s_feats, neigh, kpts, rs, whi, wlo, outp);
    } else {
        hipLaunchKernelGGL(kpconv_fallback, dim3(NQ / 16), dim3(256), 0, stream,
                           q_pts, s_pts, s_feats, neigh, W, kpts, outp);
    }
}